// Round 5
// baseline (323.957 us; speedup 1.0000x reference)
//
#include <hip/hip_runtime.h>
#include <math.h>

#define TPB 192

// ---- LDS layout (float offsets), lifetime-overlaid; vector-read bases are
// provably aligned (sm __align__(16); float4 offsets %4==0, float2 %2==0).
// x   [0,784)       staged input; dead after dyn phase
// c1  [784,1840)    conv7 out [8][11][12] (stride-12 rows -> float2 reads)
// f   [1840,1930)   conv5 out  (inside future-y, dead before dyn)
// h   [1932,1964)   fc1 out    (16B aligned, dead before dyn)
// y   [784,2264)    dyn out [10][12][12], ic-stride 148 (row/col 12 of the
//                   13x13 pooled map are never read by conv2's pooled-only
//                   outputs -> not computed). 148%32=20 -> oc 2-way banks max.
// k   [2264,2304)   dyn kernels — alive while y is written, so past y's end
// P2  [2304,3604)   conv2 ic<5 half-partials [20][65]
// p3 [0,320) pf [320,420) a1 [420,470) z [472,482)   (over dead x)
#define OX    0
#define OC1   784
#define OF    1840
#define OH    1932
#define OY    784
#define YIC   148
#define OK2   2264
#define OP2   2304
#define OP3   0
#define OPF   320
#define OA1   420
#define OZ    472
#define SM_TOT 3604   // 14416 B -> 10 blocks/CU (LDS 11, wave cap 10). Non-binding.

// Packed-weight workspace layout (floats). Rows padded 25->28 / 49->64 so
// every weight load is float4 (scalar stride-25 loads were ~950 wave-level
// VMEM instrs/block). Filled by repack_weights prep kernel.
#define OW1P  0      // [8 oc][8 t][8]   (t<7,k<7 used)
#define OW2P  512    // [10 oc][8 ic][28] (25 used)
#define OC2P  2752   // [20 oc][10 ic][28]
#define WS_FLOATS 8352   // 33408 B

__global__ void repack_weights(const float* __restrict__ kf_w1,
                               const float* __restrict__ kf_w2,
                               const float* __restrict__ conv2_w,
                               float* __restrict__ ws)
{
    int i = blockIdx.x * blockDim.x + threadIdx.x;
    if (i < 512) {
        int oc = i >> 6, t = (i >> 3) & 7, k = i & 7;
        ws[OW1P + i] = (t < 7 && k < 7) ? kf_w1[oc * 49 + t * 7 + k] : 0.f;
    }
    if (i < 2240) {
        int rem = i % 28, row = i / 28;          // row = oc*8+ic
        ws[OW2P + i] = (rem < 25) ? kf_w2[row * 25 + rem] : 0.f;
    }
    if (i < 5600) {
        int rem = i % 28, row = i / 28;          // row = oc*10+ic
        ws[OC2P + i] = (rem < 25) ? conv2_w[row * 25 + rem] : 0.f;
    }
}

// R5: R4 + (a) float4 weight loads from repacked d_ws (template fallback to
// direct scalar loads if ws too small), (b) y shrunk to the 12x12 live region
// (dyn -8% work), (c) LDS 14416 B. Keep R4's fully-unrolled schedule — R3
// proved forced rolling serializes (VALUBusy 67->56).
template <bool PACKED>
__global__ __launch_bounds__(TPB) void fused_forward(
    const float* __restrict__ x,
    const float* __restrict__ kf_w1, const float* __restrict__ kf_b1,
    const float* __restrict__ kf_w2, const float* __restrict__ kf_b2,
    const float* __restrict__ kf_fc1_w, const float* __restrict__ kf_fc1_b,
    const float* __restrict__ kf_fc2_w, const float* __restrict__ kf_fc2_b,
    const float* __restrict__ conv2_w, const float* __restrict__ conv2_b,
    const float* __restrict__ fc1_w, const float* __restrict__ fc1_b,
    const float* __restrict__ fc2_w, const float* __restrict__ fc2_b,
    const float* __restrict__ wpk,
    float* __restrict__ out)
{
    __shared__ __align__(16) float sm[SM_TOT];
    const int tid = threadIdx.x;
    const int n = blockIdx.x;

    // ---- stage 0: stage x into LDS (float4) ----
    {
        const float4* xg = (const float4*)(x + (long long)n * 784);
        float4* d = (float4*)&sm[OX];
        for (int i = tid; i < 196; i += TPB) d[i] = xg[i];
    }
    __syncthreads();

    // ---- conv7 (28->22) + pool (->11) + relu ----
    // oc = tid&7 -> 8-lane broadcast; x rows as float2 (start 10h even).
    if (tid < 176) {
        int oc = tid & 7;
        int r  = tid >> 3;
        int py = r >> 1;
        int h  = r & 1;
        const int cc0 = 10 * h;
        float c[2][12];
        #pragma unroll
        for (int r2 = 0; r2 < 2; ++r2)
            #pragma unroll
            for (int i = 0; i < 12; ++i) c[r2][i] = 0.f;
        float wc[7], wp[7];
        if constexpr (PACKED) {
            const float4* wt = (const float4*)(wpk + OW1P + oc * 64);
            float4 a = wt[0], b = wt[1];
            wc[0]=a.x; wc[1]=a.y; wc[2]=a.z; wc[3]=a.w; wc[4]=b.x; wc[5]=b.y; wc[6]=b.z;
        } else {
            const float* wg = kf_w1 + oc * 49;
            #pragma unroll
            for (int i = 0; i < 7; ++i) wc[i] = wg[i];
        }
        #pragma unroll
        for (int t = 0; t < 8; ++t) {
            const float2* xs = (const float2*)&sm[OX + (2 * py + t) * 28 + cc0];
            float row[18];
            #pragma unroll
            for (int i = 0; i < 9; ++i) { float2 q = xs[i]; row[2*i] = q.x; row[2*i+1] = q.y; }
            if (t <= 6) {
                #pragma unroll
                for (int kx = 0; kx < 7; ++kx)
                    #pragma unroll
                    for (int cc = 0; cc < 12; ++cc)
                        c[0][cc] = fmaf(wc[kx], row[cc + kx], c[0][cc]);
            }
            if (t >= 1) {
                #pragma unroll
                for (int kx = 0; kx < 7; ++kx)
                    #pragma unroll
                    for (int cc = 0; cc < 12; ++cc)
                        c[1][cc] = fmaf(wp[kx], row[cc + kx], c[1][cc]);
            }
            #pragma unroll
            for (int i = 0; i < 7; ++i) wp[i] = wc[i];
            if (t < 7) {
                if constexpr (PACKED) {
                    const float4* wt = (const float4*)(wpk + OW1P + oc * 64 + (t + 1) * 8);
                    float4 a = wt[0], b = wt[1];
                    wc[0]=a.x; wc[1]=a.y; wc[2]=a.z; wc[3]=a.w; wc[4]=b.x; wc[5]=b.y; wc[6]=b.z;
                } else {
                    const float* wn = kf_w1 + oc * 49 + (t + 1) * 7;
                    #pragma unroll
                    for (int i = 0; i < 7; ++i) wc[i] = wn[i];
                }
            }
        }
        float b = kf_b1[oc];
        #pragma unroll
        for (int j = 0; j < 6; ++j) {
            float m = fmaxf(fmaxf(c[0][2 * j], c[0][2 * j + 1]),
                            fmaxf(c[1][2 * j], c[1][2 * j + 1]));
            sm[OC1 + oc * 132 + py * 12 + 5 * h + j] = fmaxf(m + b, 0.f);
        }
    }
    __syncthreads();

    // ---- conv5 (11->7) + pool (->3) + relu; c1 rows as float2 (stride 12) ----
    if (tid < 90) {
        int oc = tid % 10, r = tid / 10;
        int py = r / 3, px = r % 3;
        float a00 = 0.f, a01 = 0.f, a10 = 0.f, a11 = 0.f;
        for (int ic = 0; ic < 8; ++ic) {
            float w[28];
            if constexpr (PACKED) {
                const float4* wt = (const float4*)(wpk + OW2P + (oc * 8 + ic) * 28);
                #pragma unroll
                for (int i = 0; i < 7; ++i) ((float4*)w)[i] = wt[i];
            } else {
                const float* wg = kf_w2 + (oc * 8 + ic) * 25;
                #pragma unroll
                for (int i = 0; i < 25; ++i) w[i] = wg[i];
            }
            const float* xb = &sm[OC1 + ic * 132 + 2 * py * 12 + 2 * px];
            float cur[6], nxt[6];
            {
                const float2* xr = (const float2*)xb;
                #pragma unroll
                for (int i = 0; i < 3; ++i) { float2 q = xr[i]; cur[2*i] = q.x; cur[2*i+1] = q.y; }
            }
            #pragma unroll
            for (int ky = 0; ky < 5; ++ky) {
                const float2* xr = (const float2*)(xb + (ky + 1) * 12);
                #pragma unroll
                for (int i = 0; i < 3; ++i) { float2 q = xr[i]; nxt[2*i] = q.x; nxt[2*i+1] = q.y; }
                #pragma unroll
                for (int kx = 0; kx < 5; ++kx) {
                    float wv = w[ky * 5 + kx];
                    a00 = fmaf(wv, cur[kx],     a00);
                    a01 = fmaf(wv, cur[kx + 1], a01);
                    a10 = fmaf(wv, nxt[kx],     a10);
                    a11 = fmaf(wv, nxt[kx + 1], a11);
                }
                #pragma unroll
                for (int i = 0; i < 6; ++i) cur[i] = nxt[i];
            }
        }
        float m = fmaxf(fmaxf(a00, a01), fmaxf(a10, a11)) + kf_b2[oc];
        sm[OF + oc * 9 + py * 3 + px] = fmaxf(m, 0.f);
    }
    __syncthreads();

    // ---- fc 90->32 + relu, then fc 32->40: both wave 0, no barrier between ----
    if (tid < 32) {
        float acc = kf_fc1_b[tid];
        const float2* wr = (const float2*)&kf_fc1_w[tid * 90];   // 8B-aligned
        const float2* ff = (const float2*)&sm[OF];               // OF even
        for (int i = 0; i < 45; ++i) {
            float2 wv = wr[i], fv = ff[i];
            acc = fmaf(wv.x, fv.x, acc);
            acc = fmaf(wv.y, fv.y, acc);
        }
        sm[OH + tid] = fmaxf(acc, 0.f);
    }
    if (tid < 40) {
        float acc = kf_fc2_b[tid];
        const float4* wr = (const float4*)&kf_fc2_w[tid * 32];   // 16B-aligned
        const float4* hh = (const float4*)&sm[OH];               // OH % 4 == 0
        #pragma unroll
        for (int i = 0; i < 8; ++i) {
            float4 wv = wr[i], hv = hh[i];
            acc = fmaf(wv.x, hv.x, acc);
            acc = fmaf(wv.y, hv.y, acc);
            acc = fmaf(wv.z, hv.z, acc);
            acc = fmaf(wv.w, hv.w, acc);
        }
        sm[OK2 + tid] = acc;
    }
    __syncthreads();

    // ---- dynamic 2x2 conv + pool + relu; only the 12x12 outputs conv2 reads ----
    if (tid < 120) {
        int oc = tid % 10, py = tid / 10;      // py 0..11
        float4 kv = *(const float4*)&sm[OK2 + oc * 4];           // OK2 % 4 == 0
        float k0 = kv.x, k1 = kv.y, k2 = kv.z, k3 = kv.w;
        const float* x0 = &sm[OX + 2 * py * 28];
        const float* x1 = x0 + 28;
        const float* x2 = x0 + 56;
        float2 q0 = *(const float2*)&x0[0];
        float2 q1 = *(const float2*)&x1[0];
        float2 q2 = *(const float2*)&x2[0];
        float A0 = q0.x, B0 = q0.y;
        float A1 = q1.x, B1 = q1.y;
        float A2 = q2.x, B2 = q2.y;
        float* yo = &sm[OY + oc * YIC + py * 12];
        #pragma unroll
        for (int j = 0; j < 12; ++j) {
            float2 r0 = *(const float2*)&x0[2 * j + 2];   // (C, nextB)
            float2 r1 = *(const float2*)&x1[2 * j + 2];
            float2 r2 = *(const float2*)&x2[2 * j + 2];
            float C0 = r0.x, C1 = r1.x, C2 = r2.x;
            float c00 = A0 * k0 + B0 * k1 + A1 * k2 + B1 * k3;
            float c01 = B0 * k0 + C0 * k1 + B1 * k2 + C1 * k3;
            float c10 = A1 * k0 + B1 * k1 + A2 * k2 + B2 * k3;
            float c11 = B1 * k0 + C1 * k1 + B2 * k2 + C2 * k3;
            float m = fmaxf(fmaxf(c00, c01), fmaxf(c10, c11));
            yo[j] = fmaxf(m, 0.f);
            A0 = C0; A1 = C1; A2 = C2;
            B0 = r0.y; B1 = r1.y; B2 = r2.y;
        }
    }
    __syncthreads();

    // ---- conv2 5x5: only the 8x8 outputs the pool reads; y rows as 3x float4.
    // h2=0 writes partials to P2; h2=1 keeps acc in regs across barrier.
    const int oc2 = tid % 20;
    const int q2i = tid / 20;
    const int h2  = q2i & 1;
    const int rg2 = q2i >> 1;
    float a2[2][8];
    if (tid < 160) {
        int r0 = 2 * rg2;
        #pragma unroll
        for (int r = 0; r < 2; ++r)
            #pragma unroll
            for (int i = 0; i < 8; ++i) a2[r][i] = 0.f;
        for (int icg = 0; icg < 5; ++icg) {
            int ic = 5 * h2 + icg;
            float w[28];
            if constexpr (PACKED) {
                const float4* wt = (const float4*)(wpk + OC2P + (oc2 * 10 + ic) * 28);
                #pragma unroll
                for (int i = 0; i < 7; ++i) ((float4*)w)[i] = wt[i];
            } else {
                const float* wg = conv2_w + (oc2 * 10 + ic) * 25;
                #pragma unroll
                for (int i = 0; i < 25; ++i) w[i] = wg[i];
            }
            const float* yb = &sm[OY + ic * YIC + r0 * 12];
            float row[12];
            #pragma unroll
            for (int u = 0; u < 6; ++u) {
                const float4* ys = (const float4*)(yb + u * 12);  // 16B-aligned
                #pragma unroll
                for (int i = 0; i < 3; ++i) {
                    float4 q = ys[i];
                    row[4*i] = q.x; row[4*i+1] = q.y; row[4*i+2] = q.z; row[4*i+3] = q.w;
                }
                #pragma unroll
                for (int rr = 0; rr < 2; ++rr) {
                    int ky = u - rr;
                    if (ky >= 0 && ky <= 4) {
                        #pragma unroll
                        for (int kx = 0; kx < 5; ++kx)
                            #pragma unroll
                            for (int cx = 0; cx < 8; ++cx)
                                a2[rr][cx] = fmaf(w[ky * 5 + kx], row[cx + kx], a2[rr][cx]);
                    }
                }
            }
        }
        if (h2 == 0) {
            int r0w = 2 * rg2;
            #pragma unroll
            for (int rr = 0; rr < 2; ++rr)
                #pragma unroll
                for (int cx = 0; cx < 8; ++cx)
                    sm[OP2 + oc2 * 65 + (r0w + rr) * 8 + cx] = a2[rr][cx];
        }
    }
    __syncthreads();

    // ---- combine halves + bias + pool + relu -> p3[20,4,4] (80 h2=1 threads) ----
    if (tid < 160 && h2 == 1) {
        float b = conv2_b[oc2];
        const float* p0 = &sm[OP2 + oc2 * 65 + (2 * rg2) * 8];
        #pragma unroll
        for (int px = 0; px < 4; ++px) {
            float c00 = b + a2[0][2 * px]     + p0[2 * px];
            float c01 = b + a2[0][2 * px + 1] + p0[2 * px + 1];
            float c10 = b + a2[1][2 * px]     + p0[8 + 2 * px];
            float c11 = b + a2[1][2 * px + 1] + p0[8 + 2 * px + 1];
            float m = fmaxf(fmaxf(c00, c01), fmaxf(c10, c11));
            sm[OP3 + oc2 * 16 + rg2 * 4 + px] = fmaxf(m, 0.f);
        }
    }
    __syncthreads();

    // ---- fc 320->50, 2-way k-split (100 threads, 40 float4 each, uniform) ----
    if (tid < 100) {
        int g = tid / 50, o = tid % 50;
        const float4* wr4 = (const float4*)&fc1_w[o * 320 + g * 160];  // 16B-aligned
        const float4* pp4 = (const float4*)&sm[OP3 + g * 160];
        float acc = 0.f;
        for (int i = 0; i < 40; ++i) {
            float4 wv = wr4[i], pv = pp4[i];
            acc = fmaf(wv.x, pv.x, acc);
            acc = fmaf(wv.y, pv.y, acc);
            acc = fmaf(wv.z, pv.z, acc);
            acc = fmaf(wv.w, pv.w, acc);
        }
        sm[OPF + tid] = acc;
    }
    __syncthreads();

    // ---- tail: all wave 0, barrier-free (intra-wave LDS ordering) ----
    if (tid < 50) {
        float acc = fc1_b[tid] + sm[OPF + tid] + sm[OPF + 50 + tid];
        sm[OA1 + tid] = fmaxf(acc, 0.f);
    }
    if (tid < 10) {
        float acc = fc2_b[tid];
        const float2* wr = (const float2*)&fc2_w[tid * 50];   // 8B-aligned
        #pragma unroll
        for (int i = 0; i < 25; ++i) {
            float2 wv = wr[i];
            acc = fmaf(wv.x, sm[OA1 + 2 * i], acc);
            acc = fmaf(wv.y, sm[OA1 + 2 * i + 1], acc);
        }
        sm[OZ + tid] = acc;
    }
    if (tid < 10) {
        float m = sm[OZ + 0];
        #pragma unroll
        for (int i = 1; i < 10; ++i) m = fmaxf(m, sm[OZ + i]);
        float s = 0.f;
        #pragma unroll
        for (int i = 0; i < 10; ++i) s += expf(sm[OZ + i] - m);
        out[n * 10 + tid] = sm[OZ + tid] - m - logf(s);
    }
}

extern "C" void kernel_launch(void* const* d_in, const int* in_sizes, int n_in,
                              void* d_out, int out_size, void* d_ws, size_t ws_size,
                              hipStream_t stream) {
    const float* x        = (const float*)d_in[0];
    const float* kf_w1    = (const float*)d_in[1];
    const float* kf_b1    = (const float*)d_in[2];
    const float* kf_w2    = (const float*)d_in[3];
    const float* kf_b2    = (const float*)d_in[4];
    const float* kf_fc1_w = (const float*)d_in[5];
    const float* kf_fc1_b = (const float*)d_in[6];
    const float* kf_fc2_w = (const float*)d_in[7];
    const float* kf_fc2_b = (const float*)d_in[8];
    const float* conv2_w  = (const float*)d_in[9];
    const float* conv2_b  = (const float*)d_in[10];
    const float* fc1_w    = (const float*)d_in[11];
    const float* fc1_b    = (const float*)d_in[12];
    const float* fc2_w    = (const float*)d_in[13];
    const float* fc2_b    = (const float*)d_in[14];

    const int N = in_sizes[0] / 784;   // 8192
    const bool packed = (d_ws != nullptr) && (ws_size >= WS_FLOATS * sizeof(float));

    if (packed) {
        repack_weights<<<22, 256, 0, stream>>>(kf_w1, kf_w2, conv2_w, (float*)d_ws);
        fused_forward<true><<<N, TPB, 0, stream>>>(
            x, kf_w1, kf_b1, kf_w2, kf_b2, kf_fc1_w, kf_fc1_b, kf_fc2_w, kf_fc2_b,
            conv2_w, conv2_b, fc1_w, fc1_b, fc2_w, fc2_b,
            (const float*)d_ws, (float*)d_out);
    } else {
        fused_forward<false><<<N, TPB, 0, stream>>>(
            x, kf_w1, kf_b1, kf_w2, kf_b2, kf_fc1_w, kf_fc1_b, kf_fc2_w, kf_fc2_b,
            conv2_w, conv2_b, fc1_w, fc1_b, fc2_w, fc2_b,
            nullptr, (float*)d_out);
    }
}

// Round 6
// 274.568 us; speedup vs baseline: 1.1799x; 1.1799x over previous
//
#include <hip/hip_runtime.h>
#include <math.h>

#define TPB 192

// ---- LDS layout (float offsets), lifetime-overlaid; vector-read bases are
// provably aligned (sm __align__(16); float4 offsets %4==0, float2 %2==0).
// x   [0,784)       staged input; dead after dyn phase
// c1  [784,1840)    conv7 out [8][11][12] (stride-12 rows -> float2 reads)
// f   [1840,1930)   conv5 out  (inside future-y, dead before dyn)
// h   [1932,1964)   fc1 out    (16B aligned, dead before dyn)
// y   [784,2264)    dyn out [10][12][12], ic-stride 148 (row/col 12 of the
//                   13x13 pooled map are never read by conv2's pooled-only
//                   outputs -> not computed). conv2 4-addr read groups land on
//                   banks {0-3,24-27,4-7,28-31} — conflict-free (verified).
// k   [2264,2304)   dyn kernels — alive while y is written, so past y's end
// P2  [2304,3604)   conv2 ic<5 half-partials [20][65]
// p3 [0,320) pf [320,420) a1 [420,470) z [472,482)   (over dead x)
#define OX    0
#define OC1   784
#define OF    1840
#define OH    1932
#define OY    784
#define YIC   148
#define OK2   2264
#define OP2   2304
#define OP3   0
#define OPF   320
#define OA1   420
#define OZ    472
#define SM_TOT 3604   // 14416 B. Occupancy caps non-binding (R0-R2 null results).

// R6: isolation round. R5's packed-weight float4 loads DOUBLED stall cycles
// (busy 389K->368K but dur 219->268us) — reverted to R4's scalar weight loads
// (compiler fully unrolls and schedules 25 independent dwords; proven 219us).
// Kept from R5: y 12x12 live-region shrink + dyn 120-thread map (mechanically
// independent, conflict-verified). R3 lesson: never force-roll the hot loops.
__global__ __launch_bounds__(TPB) void fused_forward(
    const float* __restrict__ x,
    const float* __restrict__ kf_w1, const float* __restrict__ kf_b1,
    const float* __restrict__ kf_w2, const float* __restrict__ kf_b2,
    const float* __restrict__ kf_fc1_w, const float* __restrict__ kf_fc1_b,
    const float* __restrict__ kf_fc2_w, const float* __restrict__ kf_fc2_b,
    const float* __restrict__ conv2_w, const float* __restrict__ conv2_b,
    const float* __restrict__ fc1_w, const float* __restrict__ fc1_b,
    const float* __restrict__ fc2_w, const float* __restrict__ fc2_b,
    float* __restrict__ out)
{
    __shared__ __align__(16) float sm[SM_TOT];
    const int tid = threadIdx.x;
    const int n = blockIdx.x;

    // ---- stage 0: stage x into LDS (float4) ----
    {
        const float4* xg = (const float4*)(x + (long long)n * 784);
        float4* d = (float4*)&sm[OX];
        for (int i = tid; i < 196; i += TPB) d[i] = xg[i];
    }
    __syncthreads();

    // ---- conv7 (28->22) + pool (->11) + relu ----
    // oc = tid&7 -> 8-lane broadcast; x rows as float2 (start 10h even).
    if (tid < 176) {
        int oc = tid & 7;
        int r  = tid >> 3;
        int py = r >> 1;
        int h  = r & 1;
        const int cc0 = 10 * h;
        float c[2][12];
        #pragma unroll
        for (int r2 = 0; r2 < 2; ++r2)
            #pragma unroll
            for (int i = 0; i < 12; ++i) c[r2][i] = 0.f;
        float wc[7], wp[7];
        const float* wg = kf_w1 + oc * 49;
        #pragma unroll
        for (int i = 0; i < 7; ++i) wc[i] = wg[i];
        #pragma unroll
        for (int t = 0; t < 8; ++t) {
            const float2* xs = (const float2*)&sm[OX + (2 * py + t) * 28 + cc0];
            float row[18];
            #pragma unroll
            for (int i = 0; i < 9; ++i) { float2 q = xs[i]; row[2*i] = q.x; row[2*i+1] = q.y; }
            if (t <= 6) {
                #pragma unroll
                for (int kx = 0; kx < 7; ++kx)
                    #pragma unroll
                    for (int cc = 0; cc < 12; ++cc)
                        c[0][cc] = fmaf(wc[kx], row[cc + kx], c[0][cc]);
            }
            if (t >= 1) {
                #pragma unroll
                for (int kx = 0; kx < 7; ++kx)
                    #pragma unroll
                    for (int cc = 0; cc < 12; ++cc)
                        c[1][cc] = fmaf(wp[kx], row[cc + kx], c[1][cc]);
            }
            #pragma unroll
            for (int i = 0; i < 7; ++i) wp[i] = wc[i];
            if (t < 7) {
                const float* wn = wg + (t + 1) * 7;
                #pragma unroll
                for (int i = 0; i < 7; ++i) wc[i] = wn[i];
            }
        }
        float b = kf_b1[oc];
        #pragma unroll
        for (int j = 0; j < 6; ++j) {
            float m = fmaxf(fmaxf(c[0][2 * j], c[0][2 * j + 1]),
                            fmaxf(c[1][2 * j], c[1][2 * j + 1]));
            sm[OC1 + oc * 132 + py * 12 + 5 * h + j] = fmaxf(m + b, 0.f);
        }
    }
    __syncthreads();

    // ---- conv5 (11->7) + pool (->3) + relu; c1 rows as float2 (stride 12) ----
    if (tid < 90) {
        int oc = tid % 10, r = tid / 10;
        int py = r / 3, px = r % 3;
        float a00 = 0.f, a01 = 0.f, a10 = 0.f, a11 = 0.f;
        for (int ic = 0; ic < 8; ++ic) {
            float w[25];
            const float* wg = kf_w2 + (oc * 8 + ic) * 25;
            #pragma unroll
            for (int i = 0; i < 25; ++i) w[i] = wg[i];
            const float* xb = &sm[OC1 + ic * 132 + 2 * py * 12 + 2 * px];
            float cur[6], nxt[6];
            {
                const float2* xr = (const float2*)xb;
                #pragma unroll
                for (int i = 0; i < 3; ++i) { float2 q = xr[i]; cur[2*i] = q.x; cur[2*i+1] = q.y; }
            }
            #pragma unroll
            for (int ky = 0; ky < 5; ++ky) {
                const float2* xr = (const float2*)(xb + (ky + 1) * 12);
                #pragma unroll
                for (int i = 0; i < 3; ++i) { float2 q = xr[i]; nxt[2*i] = q.x; nxt[2*i+1] = q.y; }
                #pragma unroll
                for (int kx = 0; kx < 5; ++kx) {
                    float wv = w[ky * 5 + kx];
                    a00 = fmaf(wv, cur[kx],     a00);
                    a01 = fmaf(wv, cur[kx + 1], a01);
                    a10 = fmaf(wv, nxt[kx],     a10);
                    a11 = fmaf(wv, nxt[kx + 1], a11);
                }
                #pragma unroll
                for (int i = 0; i < 6; ++i) cur[i] = nxt[i];
            }
        }
        float m = fmaxf(fmaxf(a00, a01), fmaxf(a10, a11)) + kf_b2[oc];
        sm[OF + oc * 9 + py * 3 + px] = fmaxf(m, 0.f);
    }
    __syncthreads();

    // ---- fc 90->32 + relu, then fc 32->40: both wave 0, no barrier between ----
    if (tid < 32) {
        float acc = kf_fc1_b[tid];
        const float2* wr = (const float2*)&kf_fc1_w[tid * 90];   // 8B-aligned
        const float2* ff = (const float2*)&sm[OF];               // OF even
        for (int i = 0; i < 45; ++i) {
            float2 wv = wr[i], fv = ff[i];
            acc = fmaf(wv.x, fv.x, acc);
            acc = fmaf(wv.y, fv.y, acc);
        }
        sm[OH + tid] = fmaxf(acc, 0.f);
    }
    if (tid < 40) {
        float acc = kf_fc2_b[tid];
        const float4* wr = (const float4*)&kf_fc2_w[tid * 32];   // 16B-aligned
        const float4* hh = (const float4*)&sm[OH];               // OH % 4 == 0
        #pragma unroll
        for (int i = 0; i < 8; ++i) {
            float4 wv = wr[i], hv = hh[i];
            acc = fmaf(wv.x, hv.x, acc);
            acc = fmaf(wv.y, hv.y, acc);
            acc = fmaf(wv.z, hv.z, acc);
            acc = fmaf(wv.w, hv.w, acc);
        }
        sm[OK2 + tid] = acc;
    }
    __syncthreads();

    // ---- dynamic 2x2 conv + pool + relu; only the 12x12 outputs conv2 reads ----
    if (tid < 120) {
        int oc = tid % 10, py = tid / 10;      // py 0..11
        float4 kv = *(const float4*)&sm[OK2 + oc * 4];           // OK2 % 4 == 0
        float k0 = kv.x, k1 = kv.y, k2 = kv.z, k3 = kv.w;
        const float* x0 = &sm[OX + 2 * py * 28];
        const float* x1 = x0 + 28;
        const float* x2 = x0 + 56;
        float2 q0 = *(const float2*)&x0[0];
        float2 q1 = *(const float2*)&x1[0];
        float2 q2 = *(const float2*)&x2[0];
        float A0 = q0.x, B0 = q0.y;
        float A1 = q1.x, B1 = q1.y;
        float A2 = q2.x, B2 = q2.y;
        float* yo = &sm[OY + oc * YIC + py * 12];
        #pragma unroll
        for (int j = 0; j < 12; ++j) {
            float2 r0 = *(const float2*)&x0[2 * j + 2];   // (C, nextB)
            float2 r1 = *(const float2*)&x1[2 * j + 2];
            float2 r2 = *(const float2*)&x2[2 * j + 2];
            float C0 = r0.x, C1 = r1.x, C2 = r2.x;
            float c00 = A0 * k0 + B0 * k1 + A1 * k2 + B1 * k3;
            float c01 = B0 * k0 + C0 * k1 + B1 * k2 + C1 * k3;
            float c10 = A1 * k0 + B1 * k1 + A2 * k2 + B2 * k3;
            float c11 = B1 * k0 + C1 * k1 + B2 * k2 + C2 * k3;
            float m = fmaxf(fmaxf(c00, c01), fmaxf(c10, c11));
            yo[j] = fmaxf(m, 0.f);
            A0 = C0; A1 = C1; A2 = C2;
            B0 = r0.y; B1 = r1.y; B2 = r2.y;
        }
    }
    __syncthreads();

    // ---- conv2 5x5: only the 8x8 outputs the pool reads; y rows as 3x float4.
    // h2=0 writes partials to P2; h2=1 keeps acc in regs across barrier.
    const int oc2 = tid % 20;
    const int q2i = tid / 20;
    const int h2  = q2i & 1;
    const int rg2 = q2i >> 1;
    float a2[2][8];
    if (tid < 160) {
        int r0 = 2 * rg2;
        #pragma unroll
        for (int r = 0; r < 2; ++r)
            #pragma unroll
            for (int i = 0; i < 8; ++i) a2[r][i] = 0.f;
        for (int icg = 0; icg < 5; ++icg) {
            int ic = 5 * h2 + icg;
            float w[25];
            const float* wg = conv2_w + (oc2 * 10 + ic) * 25;
            #pragma unroll
            for (int i = 0; i < 25; ++i) w[i] = wg[i];
            const float* yb = &sm[OY + ic * YIC + r0 * 12];
            float row[12];
            #pragma unroll
            for (int u = 0; u < 6; ++u) {
                const float4* ys = (const float4*)(yb + u * 12);  // 16B-aligned
                #pragma unroll
                for (int i = 0; i < 3; ++i) {
                    float4 q = ys[i];
                    row[4*i] = q.x; row[4*i+1] = q.y; row[4*i+2] = q.z; row[4*i+3] = q.w;
                }
                #pragma unroll
                for (int rr = 0; rr < 2; ++rr) {
                    int ky = u - rr;
                    if (ky >= 0 && ky <= 4) {
                        #pragma unroll
                        for (int kx = 0; kx < 5; ++kx)
                            #pragma unroll
                            for (int cx = 0; cx < 8; ++cx)
                                a2[rr][cx] = fmaf(w[ky * 5 + kx], row[cx + kx], a2[rr][cx]);
                    }
                }
            }
        }
        if (h2 == 0) {
            int r0w = 2 * rg2;
            #pragma unroll
            for (int rr = 0; rr < 2; ++rr)
                #pragma unroll
                for (int cx = 0; cx < 8; ++cx)
                    sm[OP2 + oc2 * 65 + (r0w + rr) * 8 + cx] = a2[rr][cx];
        }
    }
    __syncthreads();

    // ---- combine halves + bias + pool + relu -> p3[20,4,4] (80 h2=1 threads) ----
    if (tid < 160 && h2 == 1) {
        float b = conv2_b[oc2];
        const float* p0 = &sm[OP2 + oc2 * 65 + (2 * rg2) * 8];
        #pragma unroll
        for (int px = 0; px < 4; ++px) {
            float c00 = b + a2[0][2 * px]     + p0[2 * px];
            float c01 = b + a2[0][2 * px + 1] + p0[2 * px + 1];
            float c10 = b + a2[1][2 * px]     + p0[8 + 2 * px];
            float c11 = b + a2[1][2 * px + 1] + p0[8 + 2 * px + 1];
            float m = fmaxf(fmaxf(c00, c01), fmaxf(c10, c11));
            sm[OP3 + oc2 * 16 + rg2 * 4 + px] = fmaxf(m, 0.f);
        }
    }
    __syncthreads();

    // ---- fc 320->50, 2-way k-split (100 threads, 40 float4 each, uniform) ----
    if (tid < 100) {
        int g = tid / 50, o = tid % 50;
        const float4* wr4 = (const float4*)&fc1_w[o * 320 + g * 160];  // 16B-aligned
        const float4* pp4 = (const float4*)&sm[OP3 + g * 160];
        float acc = 0.f;
        for (int i = 0; i < 40; ++i) {
            float4 wv = wr4[i], pv = pp4[i];
            acc = fmaf(wv.x, pv.x, acc);
            acc = fmaf(wv.y, pv.y, acc);
            acc = fmaf(wv.z, pv.z, acc);
            acc = fmaf(wv.w, pv.w, acc);
        }
        sm[OPF + tid] = acc;
    }
    __syncthreads();

    // ---- tail: all wave 0, barrier-free (intra-wave LDS ordering) ----
    if (tid < 50) {
        float acc = fc1_b[tid] + sm[OPF + tid] + sm[OPF + 50 + tid];
        sm[OA1 + tid] = fmaxf(acc, 0.f);
    }
    if (tid < 10) {
        float acc = fc2_b[tid];
        const float2* wr = (const float2*)&fc2_w[tid * 50];   // 8B-aligned
        #pragma unroll
        for (int i = 0; i < 25; ++i) {
            float2 wv = wr[i];
            acc = fmaf(wv.x, sm[OA1 + 2 * i], acc);
            acc = fmaf(wv.y, sm[OA1 + 2 * i + 1], acc);
        }
        sm[OZ + tid] = acc;
    }
    if (tid < 10) {
        float m = sm[OZ + 0];
        #pragma unroll
        for (int i = 1; i < 10; ++i) m = fmaxf(m, sm[OZ + i]);
        float s = 0.f;
        #pragma unroll
        for (int i = 0; i < 10; ++i) s += expf(sm[OZ + i] - m);
        out[n * 10 + tid] = sm[OZ + tid] - m - logf(s);
    }
}

extern "C" void kernel_launch(void* const* d_in, const int* in_sizes, int n_in,
                              void* d_out, int out_size, void* d_ws, size_t ws_size,
                              hipStream_t stream) {
    const float* x        = (const float*)d_in[0];
    const float* kf_w1    = (const float*)d_in[1];
    const float* kf_b1    = (const float*)d_in[2];
    const float* kf_w2    = (const float*)d_in[3];
    const float* kf_b2    = (const float*)d_in[4];
    const float* kf_fc1_w = (const float*)d_in[5];
    const float* kf_fc1_b = (const float*)d_in[6];
    const float* kf_fc2_w = (const float*)d_in[7];
    const float* kf_fc2_b = (const float*)d_in[8];
    const float* conv2_w  = (const float*)d_in[9];
    const float* conv2_b  = (const float*)d_in[10];
    const float* fc1_w    = (const float*)d_in[11];
    const float* fc1_b    = (const float*)d_in[12];
    const float* fc2_w    = (const float*)d_in[13];
    const float* fc2_b    = (const float*)d_in[14];

    const int N = in_sizes[0] / 784;   // 8192

    fused_forward<<<N, TPB, 0, stream>>>(
        x, kf_w1, kf_b1, kf_w2, kf_b2, kf_fc1_w, kf_fc1_b, kf_fc2_w, kf_fc2_b,
        conv2_w, conv2_b, fc1_w, fc1_b, fc2_w, fc2_b, (float*)d_out);
}